// Round 4
// baseline (314.874 us; speedup 1.0000x reference)
//
#include <hip/hip_runtime.h>
#include <stdint.h>

#define EPSV 1e-7f
#define FDIM 512
#define BK 64
#define NROWS 65536   // 16*4096

typedef __bf16 bf16_t;
typedef bf16_t bf16x8 __attribute__((ext_vector_type(8)));
typedef unsigned short ushort8 __attribute__((ext_vector_type(8)));
typedef float f32x4 __attribute__((ext_vector_type(4)));

#define AS1 __attribute__((address_space(1)))
#define AS3 __attribute__((address_space(3)))

// RNE float -> bf16
__device__ __forceinline__ unsigned short f2bf(float f) {
  union { float f; unsigned int u; } c; c.f = f;
  unsigned int u = c.u;
  unsigned int r = u + 0x7fffu + ((u >> 16) & 1u);
  return (unsigned short)(r >> 16);
}
__device__ __forceinline__ float bf2f(unsigned short s) {
  union { unsigned int u; float f; } c; c.u = ((unsigned int)s) << 16;
  return c.f;
}

// tanh via hardware exp + rcp; clamped so e^{2x} can't overflow.
__device__ __forceinline__ float fast_tanh(float x) {
  x = fminf(15.0f, fmaxf(-15.0f, x));
  float t = __expf(2.0f * x);
  return 1.0f - 2.0f * __builtin_amdgcn_rcpf(t + 1.0f);
}

// blocks 0..16383: x fp32 -> bf16 streaming (8 elem/thread)
// blocks 16384..16639: Wt[n][k] = bf16(W[k][n]) via LDS tile transpose
__global__ __launch_bounds__(256) void convert_fused(
    const float* __restrict__ x, unsigned short* __restrict__ xbf,
    const float* __restrict__ W, unsigned short* __restrict__ Wt) {
  __shared__ unsigned short tile[32][34];
  const int t = threadIdx.x;
  if (blockIdx.x < 16384) {
    size_t i = ((size_t)blockIdx.x * 256 + t) * 8;
    float4 lo = *(const float4*)(x + i);
    float4 hi = *(const float4*)(x + i + 4);
    ushort8 v;
    v[0] = f2bf(lo.x); v[1] = f2bf(lo.y); v[2] = f2bf(lo.z); v[3] = f2bf(lo.w);
    v[4] = f2bf(hi.x); v[5] = f2bf(hi.y); v[6] = f2bf(hi.z); v[7] = f2bf(hi.w);
    *(ushort8*)(xbf + i) = v;
  } else {
    const int bi = blockIdx.x - 16384;
    const int tx = t & 31, ty = t >> 5;
    const int bn = bi & 15, bk = bi >> 4;
    const int k0 = bk * 32, n0 = bn * 32;
#pragma unroll
    for (int i = 0; i < 4; ++i) {
      int r = ty + i * 8;
      tile[r][tx] = f2bf(W[(size_t)(k0 + r) * FDIM + n0 + tx]);
    }
    __syncthreads();
#pragma unroll
    for (int i = 0; i < 4; ++i) {
      int r = ty + i * 8;
      Wt[(size_t)(n0 + r) * FDIM + k0 + tx] = tile[tx][r];
    }
  }
}

// One block = 128 rows x 128 cols (one n-chunk). A-fragments loaded DIRECTLY
// from global xbf (L2/L3-resident, 16B/lane); only B staged through LDS.
__global__ __launch_bounds__(256, 4) void gemm_score_bf(
    const unsigned short* __restrict__ xbf,
    const unsigned short* __restrict__ Wt,
    const float* __restrict__ bvec, const float* __restrict__ uvec,
    float* __restrict__ spart) {
  __shared__ unsigned short sB[128 * BK];   // [n][64k], 16B blocks XOR-swizzled
  __shared__ float score_s[128];
  __shared__ float ub_s[128], bb_s[128];

  const int t = threadIdx.x;
  const int lane = t & 63;
  const int w = t >> 6;
  const int wm = w & 1;
  const int wn = w >> 1;
  const int quad = lane >> 4;
  const int l15 = lane & 15;
  const int nch = blockIdx.x >> 9;       // temporal passes (L3 reuse of A)
  const int rt = blockIdx.x & 511;
  const int m0 = rt * 128;
  const int col0 = nch * 128;

  if (t < 128) {
    score_s[t] = 0.0f;
    ub_s[t] = uvec[col0 + t];
    bb_s[t] = bvec[col0 + t];
  }

  f32x4 acc[4][4];
#pragma unroll
  for (int mi = 0; mi < 4; ++mi)
#pragma unroll
    for (int ni = 0; ni < 4; ++ni) acc[mi][ni] = (f32x4){0.f, 0.f, 0.f, 0.f};

  // per-lane A base: row = m0 + wm*64 + mi*16 + l15, col = kbase + ks*32 + quad*8
  const unsigned short* aptr = xbf + (size_t)(m0 + wm * 64 + l15) * FDIM + quad * 8;

  for (int kc = 0; kc < FDIM / BK; ++kc) {
    const int kbase = kc * BK;
    // ---- stage B: async global->LDS 16B, swizzled source ----
#pragma unroll
    for (int i = 0; i < 4; ++i) {
      int nb = w * 32 + i * 8;
      int nl = nb + (lane >> 3);
      int j = (lane & 7) ^ (nl & 7);
      const unsigned short* g =
          Wt + (size_t)(col0 + nl) * FDIM + kbase + j * 8;
      unsigned short* l = (unsigned short*)(sB + nb * 64);
      __builtin_amdgcn_global_load_lds((AS1 void*)(g), (AS3 void*)(l), 16, 0, 0);
    }
    __syncthreads();
    // ---- MFMA over BK=64 (2 k-steps of 32); A straight from global ----
#pragma unroll
    for (int ks = 0; ks < 2; ++ks) {
      bf16x8 af[4], bfr[4];
#pragma unroll
      for (int mi = 0; mi < 4; ++mi)
        af[mi] = *(const bf16x8*)(const void*)(
            aptr + (size_t)(mi * 16) * FDIM + kbase + ks * 32);
#pragma unroll
      for (int ni = 0; ni < 4; ++ni) {
        int row = wn * 64 + ni * 16 + l15;
        int phys = (ks * 4 + quad) ^ (row & 7);
        bfr[ni] = *(const bf16x8*)(const void*)(sB + row * 64 + phys * 8);
      }
#pragma unroll
      for (int mi = 0; mi < 4; ++mi)
#pragma unroll
        for (int ni = 0; ni < 4; ++ni)
          acc[mi][ni] = __builtin_amdgcn_mfma_f32_16x16x32_bf16(
              af[mi], bfr[ni], acc[mi][ni], 0, 0, 0);
    }
    __syncthreads();
  }

  // ---- epilogue: sc = sum_n u[n] * tanh(C + b[n]) over this chunk ----
  float sc[4][4];
#pragma unroll
  for (int mi = 0; mi < 4; ++mi)
#pragma unroll
    for (int r = 0; r < 4; ++r) sc[mi][r] = 0.0f;
#pragma unroll
  for (int ni = 0; ni < 4; ++ni) {
    int cl = wn * 64 + ni * 16 + l15;
    float uu = ub_s[cl], bb = bb_s[cl];
#pragma unroll
    for (int mi = 0; mi < 4; ++mi)
#pragma unroll
      for (int r = 0; r < 4; ++r)
        sc[mi][r] += uu * fast_tanh(acc[mi][ni][r] + bb);
  }
#pragma unroll
  for (int mi = 0; mi < 4; ++mi)
#pragma unroll
    for (int r = 0; r < 4; ++r) {
      float v = sc[mi][r];
      v += __shfl_xor(v, 1); v += __shfl_xor(v, 2);
      v += __shfl_xor(v, 4); v += __shfl_xor(v, 8);
      if (l15 == 0)
        atomicAdd(&score_s[wm * 64 + mi * 16 + quad * 4 + r], v);
    }
  __syncthreads();
  if (t < 128) spart[(size_t)nch * NROWS + m0 + t] = score_s[t];
}

// Fused: per-32-row block computes score->e from the 4 spart chunks, adds
// its Sum(e) to sumE, then x.e pooling partials (atomic-free) -> ppool.
__global__ __launch_bounds__(256, 8) void pool_score(
    const unsigned short* __restrict__ xbf, const float* __restrict__ spart,
    float* __restrict__ sumE, float* __restrict__ ppool) {
  __shared__ float e_s[32];
  __shared__ float red[4][FDIM];
  const int t = threadIdx.x;
  const int c8 = t & 63, rg = t >> 6;
  const int r0 = blockIdx.x * 32;
  if (t < 32) {
    int i = r0 + t;
    float s = spart[i] + spart[i + NROWS] + spart[i + 2 * NROWS] + spart[i + 3 * NROWS];
    float e = __expf(s);
    e_s[t] = e;
    float v = e;
    v += __shfl_xor(v, 1); v += __shfl_xor(v, 2); v += __shfl_xor(v, 4);
    v += __shfl_xor(v, 8); v += __shfl_xor(v, 16);
    if (t == 0) atomicAdd(sumE, v);
  }
  __syncthreads();
  float a[8];
#pragma unroll
  for (int j = 0; j < 8; ++j) a[j] = 0.0f;
  for (int it = 0; it < 8; ++it) {
    int row = rg * 8 + it;
    ushort8 v = *(const ushort8*)(xbf + (size_t)(r0 + row) * FDIM + c8 * 8);
    float wg = e_s[row];
#pragma unroll
    for (int j = 0; j < 8; ++j) a[j] += bf2f(v[j]) * wg;
  }
  *(float4*)&red[rg][c8 * 8]     = (float4){a[0], a[1], a[2], a[3]};
  *(float4*)&red[rg][c8 * 8 + 4] = (float4){a[4], a[5], a[6], a[7]};
  __syncthreads();
  int c = t, c2 = t + 256;
  float s0 = red[0][c] + red[1][c] + red[2][c] + red[3][c];
  float s1 = red[0][c2] + red[1][c2] + red[2][c2] + red[3][c2];
  ppool[(size_t)blockIdx.x * FDIM + c]  = s0;
  ppool[(size_t)blockIdx.x * FDIM + c2] = s1;
}

// out[b,f] = inv * sum over the 128 chunk-partials of batch b.
__global__ __launch_bounds__(256) void pool_reduce(
    const float* __restrict__ ppool, const float* __restrict__ sumE,
    float* __restrict__ out) {
  const int i = blockIdx.x * 256 + threadIdx.x;   // 0..8191
  const int b = i >> 9, f = i & 511;
  float s = 0.0f;
  const float* p = ppool + (size_t)b * 128 * FDIM + f;
  for (int c = 0; c < 128; ++c) s += p[(size_t)c * FDIM];
  out[i] = s / (*sumE + EPSV);
}

// ---------------- fallback path (small ws), proven in round 2 ----------------
__global__ void convert_W_f(const float* __restrict__ W, unsigned short* __restrict__ Wt) {
  __shared__ unsigned short tile[32][34];
  const int t = threadIdx.x;
  const int tx = t & 31, ty = t >> 5;
  const int bn = blockIdx.x & 15, bk = blockIdx.x >> 4;
  const int k0 = bk * 32, n0 = bn * 32;
#pragma unroll
  for (int i = 0; i < 4; ++i) {
    int r = ty + i * 8;
    tile[r][tx] = f2bf(W[(size_t)(k0 + r) * FDIM + n0 + tx]);
  }
  __syncthreads();
#pragma unroll
  for (int i = 0; i < 4; ++i) {
    int r = ty + i * 8;
    Wt[(size_t)(n0 + r) * FDIM + k0 + tx] = tile[tx][r];
  }
}

__global__ __launch_bounds__(256, 4) void gemm_score_f32(
    const float* __restrict__ x, const unsigned short* __restrict__ Wt,
    const float* __restrict__ bvec, const float* __restrict__ uvec,
    float* __restrict__ spart) {
  __shared__ unsigned short sA[128 * BK];
  __shared__ unsigned short sB[128 * BK];
  __shared__ float score_s[128];
  __shared__ float ub_s[128], bb_s[128];
  const int t = threadIdx.x;
  const int lane = t & 63;
  const int w = t >> 6;
  const int wm = w & 1, wn = w >> 1;
  const int quad = lane >> 4, l15 = lane & 15;
  const int nch = blockIdx.x >> 9;
  const int rt = blockIdx.x & 511;
  const int m0 = rt * 128, col0 = nch * 128;
  if (t < 128) { score_s[t] = 0.0f; ub_s[t] = uvec[col0 + t]; bb_s[t] = bvec[col0 + t]; }
  f32x4 acc[4][4];
#pragma unroll
  for (int mi = 0; mi < 4; ++mi)
#pragma unroll
    for (int ni = 0; ni < 4; ++ni) acc[mi][ni] = (f32x4){0.f, 0.f, 0.f, 0.f};
  for (int kc = 0; kc < FDIM / BK; ++kc) {
    const int kbase = kc * BK;
#pragma unroll
    for (int p = 0; p < 4; ++p) {
      int slot = t + 256 * p;
      int row = slot >> 3;
      int j = (slot & 7) ^ (row & 7);
      const float* g = x + (size_t)(m0 + row) * FDIM + kbase + j * 8;
      float4 lo = *(const float4*)g;
      float4 hi = *(const float4*)(g + 4);
      ushort8 v;
      v[0] = f2bf(lo.x); v[1] = f2bf(lo.y); v[2] = f2bf(lo.z); v[3] = f2bf(lo.w);
      v[4] = f2bf(hi.x); v[5] = f2bf(hi.y); v[6] = f2bf(hi.z); v[7] = f2bf(hi.w);
      *(ushort8*)(void*)(sA + slot * 8) = v;
    }
#pragma unroll
    for (int i = 0; i < 4; ++i) {
      int nb = w * 32 + i * 8;
      int nl = nb + (lane >> 3);
      int j = (lane & 7) ^ (nl & 7);
      const unsigned short* g = Wt + (size_t)(col0 + nl) * FDIM + kbase + j * 8;
      unsigned short* l = (unsigned short*)(sB + nb * 64);
      __builtin_amdgcn_global_load_lds((AS1 void*)(g), (AS3 void*)(l), 16, 0, 0);
    }
    __syncthreads();
#pragma unroll
    for (int ks = 0; ks < 2; ++ks) {
      bf16x8 af[4], bfr[4];
#pragma unroll
      for (int mi = 0; mi < 4; ++mi) {
        int row = wm * 64 + mi * 16 + l15;
        int phys = (ks * 4 + quad) ^ (row & 7);
        af[mi] = *(const bf16x8*)(const void*)(sA + row * 64 + phys * 8);
      }
#pragma unroll
      for (int ni = 0; ni < 4; ++ni) {
        int row = wn * 64 + ni * 16 + l15;
        int phys = (ks * 4 + quad) ^ (row & 7);
        bfr[ni] = *(const bf16x8*)(const void*)(sB + row * 64 + phys * 8);
      }
#pragma unroll
      for (int mi = 0; mi < 4; ++mi)
#pragma unroll
        for (int ni = 0; ni < 4; ++ni)
          acc[mi][ni] = __builtin_amdgcn_mfma_f32_16x16x32_bf16(
              af[mi], bfr[ni], acc[mi][ni], 0, 0, 0);
    }
    __syncthreads();
  }
  float sc[4][4];
#pragma unroll
  for (int mi = 0; mi < 4; ++mi)
#pragma unroll
    for (int r = 0; r < 4; ++r) sc[mi][r] = 0.0f;
#pragma unroll
  for (int ni = 0; ni < 4; ++ni) {
    int cl = wn * 64 + ni * 16 + l15;
    float uu = ub_s[cl], bb = bb_s[cl];
#pragma unroll
    for (int mi = 0; mi < 4; ++mi)
#pragma unroll
      for (int r = 0; r < 4; ++r)
        sc[mi][r] += uu * fast_tanh(acc[mi][ni][r] + bb);
  }
#pragma unroll
  for (int mi = 0; mi < 4; ++mi)
#pragma unroll
    for (int r = 0; r < 4; ++r) {
      float v = sc[mi][r];
      v += __shfl_xor(v, 1); v += __shfl_xor(v, 2);
      v += __shfl_xor(v, 4); v += __shfl_xor(v, 8);
      if (l15 == 0)
        atomicAdd(&score_s[wm * 64 + mi * 16 + quad * 4 + r], v);
    }
  __syncthreads();
  if (t < 128) spart[(size_t)nch * NROWS + m0 + t] = score_s[t];
}

__global__ void score_exp(float* __restrict__ spart, float* __restrict__ sumE) {
  __shared__ float ws_[4];
  const int t = threadIdx.x;
  const int i = blockIdx.x * 256 + t;
  float s = spart[i] + spart[i + NROWS] + spart[i + 2 * NROWS] + spart[i + 3 * NROWS];
  float e = __expf(s);
  spart[i] = e;
  float v = e;
  v += __shfl_xor(v, 1);  v += __shfl_xor(v, 2);  v += __shfl_xor(v, 4);
  v += __shfl_xor(v, 8);  v += __shfl_xor(v, 16); v += __shfl_xor(v, 32);
  if ((t & 63) == 0) ws_[t >> 6] = v;
  __syncthreads();
  if (t == 0) atomicAdd(sumE, ws_[0] + ws_[1] + ws_[2] + ws_[3]);
}

__global__ __launch_bounds__(256) void pool_k(
    const float* __restrict__ x, const float* __restrict__ e,
    const float* __restrict__ sumE, float* __restrict__ out) {
  __shared__ float e_s[128];
  __shared__ float4 red[128];
  const int t = threadIdx.x;
  const int b = blockIdx.x >> 5, chunk = blockIdx.x & 31;
  const int g0 = b * 4096 + chunk * 128;
  if (t < 128) e_s[t] = e[g0 + t];
  __syncthreads();
  const int parity = t >> 7, f4 = t & 127;
  float ax = 0.f, ay = 0.f, az = 0.f, aw = 0.f;
  for (int r = 0; r < 64; ++r) {
    int row = r * 2 + parity;
    const float4 xv = *(const float4*)(x + (size_t)(g0 + row) * FDIM + f4 * 4);
    float wgt = e_s[row];
    ax += xv.x * wgt; ay += xv.y * wgt; az += xv.z * wgt; aw += xv.w * wgt;
  }
  if (parity) red[f4] = (float4){ax, ay, az, aw};
  __syncthreads();
  if (!parity) {
    float4 o = red[f4];
    float inv = 1.0f / (*sumE + EPSV);
    float* op = out + (size_t)b * FDIM + f4 * 4;
    atomicAdd(op + 0, (ax + o.x) * inv);
    atomicAdd(op + 1, (ay + o.y) * inv);
    atomicAdd(op + 2, (az + o.z) * inv);
    atomicAdd(op + 3, (aw + o.w) * inv);
  }
}

extern "C" void kernel_launch(void* const* d_in, const int* in_sizes, int n_in,
                              void* d_out, int out_size, void* d_ws, size_t ws_size,
                              hipStream_t stream) {
  (void)in_sizes; (void)n_in;
  const float* x = (const float*)d_in[0];
  const float* W = (const float*)d_in[1];
  const float* b = (const float*)d_in[2];
  const float* u = (const float*)d_in[3];
  float* out = (float*)d_out;

  // ws layout: Wt 512K | spart 1M | sumE (pad 256) | ppool 4M | xbf 64M
  char* p = (char*)d_ws;
  unsigned short* Wt = (unsigned short*)p;            p += (size_t)FDIM * FDIM * 2;
  float* spart = (float*)p;                           p += (size_t)4 * NROWS * 4;
  float* sumE = (float*)p;                            p += 256;
  float* ppool = (float*)p;                           p += (size_t)2048 * FDIM * 4;
  unsigned short* xbf = (unsigned short*)p;           p += (size_t)NROWS * FDIM * 2;
  const size_t need = (size_t)(p - (char*)d_ws);
  const bool big = ws_size >= need;

  hipMemsetAsync(sumE, 0, sizeof(float), stream);

  if (big) {
    convert_fused<<<dim3(16384 + 256), dim3(256), 0, stream>>>(x, xbf, W, Wt);
    gemm_score_bf<<<dim3(2048), dim3(256), 0, stream>>>(xbf, Wt, b, u, spart);
    pool_score<<<dim3(2048), dim3(256), 0, stream>>>(xbf, spart, sumE, ppool);
    pool_reduce<<<dim3(32), dim3(256), 0, stream>>>(ppool, sumE, out);
  } else {
    hipMemsetAsync(d_out, 0, (size_t)out_size * sizeof(float), stream);
    convert_W_f<<<dim3(256), dim3(256), 0, stream>>>(W, Wt);
    gemm_score_f32<<<dim3(2048), dim3(256), 0, stream>>>(x, Wt, b, u, spart);
    score_exp<<<dim3(NROWS / 256), dim3(256), 0, stream>>>(spart, sumE);
    pool_k<<<dim3(512), dim3(256), 0, stream>>>(x, spart, sumE, out);
  }
}

// Round 5
// 283.999 us; speedup vs baseline: 1.1087x; 1.1087x over previous
//
#include <hip/hip_runtime.h>
#include <stdint.h>

#define EPSV 1e-7f
#define FDIM 512
#define BK 64
#define NROWS 65536   // 16*4096

typedef __bf16 bf16_t;
typedef bf16_t bf16x8 __attribute__((ext_vector_type(8)));
typedef unsigned short ushort8 __attribute__((ext_vector_type(8)));
typedef float f32x4 __attribute__((ext_vector_type(4)));

#define AS1 __attribute__((address_space(1)))
#define AS3 __attribute__((address_space(3)))

// RNE float -> bf16
__device__ __forceinline__ unsigned short f2bf(float f) {
  union { float f; unsigned int u; } c; c.f = f;
  unsigned int u = c.u;
  unsigned int r = u + 0x7fffu + ((u >> 16) & 1u);
  return (unsigned short)(r >> 16);
}
__device__ __forceinline__ float bf2f(unsigned short s) {
  union { unsigned int u; float f; } c; c.u = ((unsigned int)s) << 16;
  return c.f;
}

// tanh via hardware exp + rcp; clamped so e^{2x} can't overflow.
__device__ __forceinline__ float fast_tanh(float x) {
  x = fminf(15.0f, fmaxf(-15.0f, x));
  float t = __expf(2.0f * x);
  return 1.0f - 2.0f * __builtin_amdgcn_rcpf(t + 1.0f);
}

// blocks 0..16383: x fp32 -> bf16 streaming (8 elem/thread)
// blocks 16384..16639: Wt[n][k] = bf16(W[k][n]) via LDS tile transpose
// block 16384, t==0 also zeroes sumE (runs before gemm/pool in stream order).
__global__ __launch_bounds__(256) void convert_fused(
    const float* __restrict__ x, unsigned short* __restrict__ xbf,
    const float* __restrict__ W, unsigned short* __restrict__ Wt,
    float* __restrict__ sumE) {
  __shared__ unsigned short tile[32][34];
  const int t = threadIdx.x;
  if (blockIdx.x < 16384) {
    size_t i = ((size_t)blockIdx.x * 256 + t) * 8;
    float4 lo = *(const float4*)(x + i);
    float4 hi = *(const float4*)(x + i + 4);
    ushort8 v;
    v[0] = f2bf(lo.x); v[1] = f2bf(lo.y); v[2] = f2bf(lo.z); v[3] = f2bf(lo.w);
    v[4] = f2bf(hi.x); v[5] = f2bf(hi.y); v[6] = f2bf(hi.z); v[7] = f2bf(hi.w);
    *(ushort8*)(xbf + i) = v;
  } else {
    const int bi = blockIdx.x - 16384;
    if (bi == 0 && t == 0) *sumE = 0.0f;
    const int tx = t & 31, ty = t >> 5;
    const int bn = bi & 15, bk = bi >> 4;
    const int k0 = bk * 32, n0 = bn * 32;
#pragma unroll
    for (int i = 0; i < 4; ++i) {
      int r = ty + i * 8;
      tile[r][tx] = f2bf(W[(size_t)(k0 + r) * FDIM + n0 + tx]);
    }
    __syncthreads();
#pragma unroll
    for (int i = 0; i < 4; ++i) {
      int r = ty + i * 8;
      Wt[(size_t)(n0 + r) * FDIM + k0 + tx] = tile[tx][r];
    }
  }
}

// One block = 128 rows x 128 cols (one n-chunk). BOTH A (from xbf) and B
// (from Wt) staged via async global_load_lds width=16, XOR-swizzled.
// nch = high grid bits so the 4 column passes are temporal (L3 reuse of A).
__global__ __launch_bounds__(256, 4) void gemm_score_st(
    const unsigned short* __restrict__ xbf,
    const unsigned short* __restrict__ Wt,
    const float* __restrict__ bvec, const float* __restrict__ uvec,
    float* __restrict__ spart) {
  __shared__ unsigned short sA[128 * BK];   // [row][64k], 16B blocks XOR-swizzled
  __shared__ unsigned short sB[128 * BK];   // [n][64k], same swizzle
  __shared__ float score_s[128];
  __shared__ float ub_s[128], bb_s[128];

  const int t = threadIdx.x;
  const int lane = t & 63;
  const int w = t >> 6;
  const int wm = w & 1;
  const int wn = w >> 1;
  const int quad = lane >> 4;
  const int l15 = lane & 15;
  const int nch = blockIdx.x >> 9;       // temporal passes
  const int rt = blockIdx.x & 511;
  const int m0 = rt * 128;
  const int col0 = nch * 128;

  if (t < 128) {
    score_s[t] = 0.0f;
    ub_s[t] = uvec[col0 + t];
    bb_s[t] = bvec[col0 + t];
  }

  f32x4 acc[4][4];
#pragma unroll
  for (int mi = 0; mi < 4; ++mi)
#pragma unroll
    for (int ni = 0; ni < 4; ++ni) acc[mi][ni] = (f32x4){0.f, 0.f, 0.f, 0.f};

  for (int kc = 0; kc < FDIM / BK; ++kc) {
    const int kbase = kc * BK;
    // ---- stage A: async global->LDS 16B from bf16 x, swizzled source ----
#pragma unroll
    for (int i = 0; i < 4; ++i) {
      int rb = w * 32 + i * 8;
      int rl = rb + (lane >> 3);
      int j = (lane & 7) ^ (rl & 7);
      const unsigned short* g = xbf + (size_t)(m0 + rl) * FDIM + kbase + j * 8;
      unsigned short* l = (unsigned short*)(sA + rb * 64);
      __builtin_amdgcn_global_load_lds((AS1 void*)(g), (AS3 void*)(l), 16, 0, 0);
    }
    // ---- stage B: async global->LDS 16B, swizzled source ----
#pragma unroll
    for (int i = 0; i < 4; ++i) {
      int nb = w * 32 + i * 8;
      int nl = nb + (lane >> 3);
      int j = (lane & 7) ^ (nl & 7);
      const unsigned short* g = Wt + (size_t)(col0 + nl) * FDIM + kbase + j * 8;
      unsigned short* l = (unsigned short*)(sB + nb * 64);
      __builtin_amdgcn_global_load_lds((AS1 void*)(g), (AS3 void*)(l), 16, 0, 0);
    }
    __syncthreads();
    // ---- MFMA over BK=64 (2 k-steps of 32) ----
#pragma unroll
    for (int ks = 0; ks < 2; ++ks) {
      bf16x8 af[4], bfr[4];
#pragma unroll
      for (int mi = 0; mi < 4; ++mi) {
        int row = wm * 64 + mi * 16 + l15;
        int phys = (ks * 4 + quad) ^ (row & 7);
        af[mi] = *(const bf16x8*)(const void*)(sA + row * 64 + phys * 8);
      }
#pragma unroll
      for (int ni = 0; ni < 4; ++ni) {
        int row = wn * 64 + ni * 16 + l15;
        int phys = (ks * 4 + quad) ^ (row & 7);
        bfr[ni] = *(const bf16x8*)(const void*)(sB + row * 64 + phys * 8);
      }
#pragma unroll
      for (int mi = 0; mi < 4; ++mi)
#pragma unroll
        for (int ni = 0; ni < 4; ++ni)
          acc[mi][ni] = __builtin_amdgcn_mfma_f32_16x16x32_bf16(
              af[mi], bfr[ni], acc[mi][ni], 0, 0, 0);
    }
    __syncthreads();
  }

  // ---- epilogue: sc = sum_n u[n] * tanh(C + b[n]) over this chunk ----
  float sc[4][4];
#pragma unroll
  for (int mi = 0; mi < 4; ++mi)
#pragma unroll
    for (int r = 0; r < 4; ++r) sc[mi][r] = 0.0f;
#pragma unroll
  for (int ni = 0; ni < 4; ++ni) {
    int cl = wn * 64 + ni * 16 + l15;
    float uu = ub_s[cl], bb = bb_s[cl];
#pragma unroll
    for (int mi = 0; mi < 4; ++mi)
#pragma unroll
      for (int r = 0; r < 4; ++r)
        sc[mi][r] += uu * fast_tanh(acc[mi][ni][r] + bb);
  }
#pragma unroll
  for (int mi = 0; mi < 4; ++mi)
#pragma unroll
    for (int r = 0; r < 4; ++r) {
      float v = sc[mi][r];
      v += __shfl_xor(v, 1); v += __shfl_xor(v, 2);
      v += __shfl_xor(v, 4); v += __shfl_xor(v, 8);
      if (l15 == 0)
        atomicAdd(&score_s[wm * 64 + mi * 16 + quad * 4 + r], v);
    }
  __syncthreads();
  if (t < 128) spart[(size_t)nch * NROWS + m0 + t] = score_s[t];
}

// Fused: per-32-row block computes score->e from the 4 spart chunks, adds
// its Sum(e) to sumE, then x.e pooling partials (atomic-free) -> ppool.
__global__ __launch_bounds__(256, 8) void pool_score(
    const unsigned short* __restrict__ xbf, const float* __restrict__ spart,
    float* __restrict__ sumE, float* __restrict__ ppool) {
  __shared__ float e_s[32];
  __shared__ float red[4][FDIM];
  const int t = threadIdx.x;
  const int c8 = t & 63, rg = t >> 6;
  const int r0 = blockIdx.x * 32;
  if (t < 32) {
    int i = r0 + t;
    float s = spart[i] + spart[i + NROWS] + spart[i + 2 * NROWS] + spart[i + 3 * NROWS];
    float e = __expf(s);
    e_s[t] = e;
    float v = e;
    v += __shfl_xor(v, 1); v += __shfl_xor(v, 2); v += __shfl_xor(v, 4);
    v += __shfl_xor(v, 8); v += __shfl_xor(v, 16);
    if (t == 0) atomicAdd(sumE, v);
  }
  __syncthreads();
  float a[8];
#pragma unroll
  for (int j = 0; j < 8; ++j) a[j] = 0.0f;
  for (int it = 0; it < 8; ++it) {
    int row = rg * 8 + it;
    ushort8 v = *(const ushort8*)(xbf + (size_t)(r0 + row) * FDIM + c8 * 8);
    float wg = e_s[row];
#pragma unroll
    for (int j = 0; j < 8; ++j) a[j] += bf2f(v[j]) * wg;
  }
  *(float4*)&red[rg][c8 * 8]     = (float4){a[0], a[1], a[2], a[3]};
  *(float4*)&red[rg][c8 * 8 + 4] = (float4){a[4], a[5], a[6], a[7]};
  __syncthreads();
  int c = t, c2 = t + 256;
  float s0 = red[0][c] + red[1][c] + red[2][c] + red[3][c];
  float s1 = red[0][c2] + red[1][c2] + red[2][c2] + red[3][c2];
  ppool[(size_t)blockIdx.x * FDIM + c]  = s0;
  ppool[(size_t)blockIdx.x * FDIM + c2] = s1;
}

// out[b,f] = inv * sum over the 128 chunk-partials of batch b.
__global__ __launch_bounds__(256) void pool_reduce(
    const float* __restrict__ ppool, const float* __restrict__ sumE,
    float* __restrict__ out) {
  const int i = blockIdx.x * 256 + threadIdx.x;   // 0..8191
  const int b = i >> 9, f = i & 511;
  float s = 0.0f;
  const float* p = ppool + (size_t)b * 128 * FDIM + f;
  for (int c = 0; c < 128; ++c) s += p[(size_t)c * FDIM];
  out[i] = s / (*sumE + EPSV);
}

// ---------------- fallback path (small ws), proven in round 2 ----------------
__global__ void convert_W_f(const float* __restrict__ W, unsigned short* __restrict__ Wt) {
  __shared__ unsigned short tile[32][34];
  const int t = threadIdx.x;
  const int tx = t & 31, ty = t >> 5;
  const int bn = blockIdx.x & 15, bk = blockIdx.x >> 4;
  const int k0 = bk * 32, n0 = bn * 32;
#pragma unroll
  for (int i = 0; i < 4; ++i) {
    int r = ty + i * 8;
    tile[r][tx] = f2bf(W[(size_t)(k0 + r) * FDIM + n0 + tx]);
  }
  __syncthreads();
#pragma unroll
  for (int i = 0; i < 4; ++i) {
    int r = ty + i * 8;
    Wt[(size_t)(n0 + r) * FDIM + k0 + tx] = tile[tx][r];
  }
}

__global__ __launch_bounds__(256, 4) void gemm_score_f32(
    const float* __restrict__ x, const unsigned short* __restrict__ Wt,
    const float* __restrict__ bvec, const float* __restrict__ uvec,
    float* __restrict__ spart) {
  __shared__ unsigned short sA[128 * BK];
  __shared__ unsigned short sB[128 * BK];
  __shared__ float score_s[128];
  __shared__ float ub_s[128], bb_s[128];
  const int t = threadIdx.x;
  const int lane = t & 63;
  const int w = t >> 6;
  const int wm = w & 1, wn = w >> 1;
  const int quad = lane >> 4, l15 = lane & 15;
  const int nch = blockIdx.x >> 9;
  const int rt = blockIdx.x & 511;
  const int m0 = rt * 128, col0 = nch * 128;
  if (t < 128) { score_s[t] = 0.0f; ub_s[t] = uvec[col0 + t]; bb_s[t] = bvec[col0 + t]; }
  f32x4 acc[4][4];
#pragma unroll
  for (int mi = 0; mi < 4; ++mi)
#pragma unroll
    for (int ni = 0; ni < 4; ++ni) acc[mi][ni] = (f32x4){0.f, 0.f, 0.f, 0.f};
  for (int kc = 0; kc < FDIM / BK; ++kc) {
    const int kbase = kc * BK;
#pragma unroll
    for (int p = 0; p < 4; ++p) {
      int slot = t + 256 * p;
      int row = slot >> 3;
      int j = (slot & 7) ^ (row & 7);
      const float* g = x + (size_t)(m0 + row) * FDIM + kbase + j * 8;
      float4 lo = *(const float4*)g;
      float4 hi = *(const float4*)(g + 4);
      ushort8 v;
      v[0] = f2bf(lo.x); v[1] = f2bf(lo.y); v[2] = f2bf(lo.z); v[3] = f2bf(lo.w);
      v[4] = f2bf(hi.x); v[5] = f2bf(hi.y); v[6] = f2bf(hi.z); v[7] = f2bf(hi.w);
      *(ushort8*)(void*)(sA + slot * 8) = v;
    }
#pragma unroll
    for (int i = 0; i < 4; ++i) {
      int nb = w * 32 + i * 8;
      int nl = nb + (lane >> 3);
      int j = (lane & 7) ^ (nl & 7);
      const unsigned short* g = Wt + (size_t)(col0 + nl) * FDIM + kbase + j * 8;
      unsigned short* l = (unsigned short*)(sB + nb * 64);
      __builtin_amdgcn_global_load_lds((AS1 void*)(g), (AS3 void*)(l), 16, 0, 0);
    }
    __syncthreads();
#pragma unroll
    for (int ks = 0; ks < 2; ++ks) {
      bf16x8 af[4], bfr[4];
#pragma unroll
      for (int mi = 0; mi < 4; ++mi) {
        int row = wm * 64 + mi * 16 + l15;
        int phys = (ks * 4 + quad) ^ (row & 7);
        af[mi] = *(const bf16x8*)(const void*)(sA + row * 64 + phys * 8);
      }
#pragma unroll
      for (int ni = 0; ni < 4; ++ni) {
        int row = wn * 64 + ni * 16 + l15;
        int phys = (ks * 4 + quad) ^ (row & 7);
        bfr[ni] = *(const bf16x8*)(const void*)(sB + row * 64 + phys * 8);
      }
#pragma unroll
      for (int mi = 0; mi < 4; ++mi)
#pragma unroll
        for (int ni = 0; ni < 4; ++ni)
          acc[mi][ni] = __builtin_amdgcn_mfma_f32_16x16x32_bf16(
              af[mi], bfr[ni], acc[mi][ni], 0, 0, 0);
    }
    __syncthreads();
  }
  float sc[4][4];
#pragma unroll
  for (int mi = 0; mi < 4; ++mi)
#pragma unroll
    for (int r = 0; r < 4; ++r) sc[mi][r] = 0.0f;
#pragma unroll
  for (int ni = 0; ni < 4; ++ni) {
    int cl = wn * 64 + ni * 16 + l15;
    float uu = ub_s[cl], bb = bb_s[cl];
#pragma unroll
    for (int mi = 0; mi < 4; ++mi)
#pragma unroll
      for (int r = 0; r < 4; ++r)
        sc[mi][r] += uu * fast_tanh(acc[mi][ni][r] + bb);
  }
#pragma unroll
  for (int mi = 0; mi < 4; ++mi)
#pragma unroll
    for (int r = 0; r < 4; ++r) {
      float v = sc[mi][r];
      v += __shfl_xor(v, 1); v += __shfl_xor(v, 2);
      v += __shfl_xor(v, 4); v += __shfl_xor(v, 8);
      if (l15 == 0)
        atomicAdd(&score_s[wm * 64 + mi * 16 + quad * 4 + r], v);
    }
  __syncthreads();
  if (t < 128) spart[(size_t)nch * NROWS + m0 + t] = score_s[t];
}

__global__ void score_exp(float* __restrict__ spart, float* __restrict__ sumE) {
  __shared__ float ws_[4];
  const int t = threadIdx.x;
  const int i = blockIdx.x * 256 + t;
  float s = spart[i] + spart[i + NROWS] + spart[i + 2 * NROWS] + spart[i + 3 * NROWS];
  float e = __expf(s);
  spart[i] = e;
  float v = e;
  v += __shfl_xor(v, 1);  v += __shfl_xor(v, 2);  v += __shfl_xor(v, 4);
  v += __shfl_xor(v, 8);  v += __shfl_xor(v, 16); v += __shfl_xor(v, 32);
  if ((t & 63) == 0) ws_[t >> 6] = v;
  __syncthreads();
  if (t == 0) atomicAdd(sumE, ws_[0] + ws_[1] + ws_[2] + ws_[3]);
}

__global__ __launch_bounds__(256) void pool_k(
    const float* __restrict__ x, const float* __restrict__ e,
    const float* __restrict__ sumE, float* __restrict__ out) {
  __shared__ float e_s[128];
  __shared__ float4 red[128];
  const int t = threadIdx.x;
  const int b = blockIdx.x >> 5, chunk = blockIdx.x & 31;
  const int g0 = b * 4096 + chunk * 128;
  if (t < 128) e_s[t] = e[g0 + t];
  __syncthreads();
  const int parity = t >> 7, f4 = t & 127;
  float ax = 0.f, ay = 0.f, az = 0.f, aw = 0.f;
  for (int r = 0; r < 64; ++r) {
    int row = r * 2 + parity;
    const float4 xv = *(const float4*)(x + (size_t)(g0 + row) * FDIM + f4 * 4);
    float wgt = e_s[row];
    ax += xv.x * wgt; ay += xv.y * wgt; az += xv.z * wgt; aw += xv.w * wgt;
  }
  if (parity) red[f4] = (float4){ax, ay, az, aw};
  __syncthreads();
  if (!parity) {
    float4 o = red[f4];
    float inv = 1.0f / (*sumE + EPSV);
    float* op = out + (size_t)b * FDIM + f4 * 4;
    atomicAdd(op + 0, (ax + o.x) * inv);
    atomicAdd(op + 1, (ay + o.y) * inv);
    atomicAdd(op + 2, (az + o.z) * inv);
    atomicAdd(op + 3, (aw + o.w) * inv);
  }
}

extern "C" void kernel_launch(void* const* d_in, const int* in_sizes, int n_in,
                              void* d_out, int out_size, void* d_ws, size_t ws_size,
                              hipStream_t stream) {
  (void)in_sizes; (void)n_in;
  const float* x = (const float*)d_in[0];
  const float* W = (const float*)d_in[1];
  const float* b = (const float*)d_in[2];
  const float* u = (const float*)d_in[3];
  float* out = (float*)d_out;

  // ws layout: Wt 512K | spart 1M | sumE (pad 256) | ppool 4M | xbf 64M
  char* p = (char*)d_ws;
  unsigned short* Wt = (unsigned short*)p;            p += (size_t)FDIM * FDIM * 2;
  float* spart = (float*)p;                           p += (size_t)4 * NROWS * 4;
  float* sumE = (float*)p;                            p += 256;
  float* ppool = (float*)p;                           p += (size_t)2048 * FDIM * 4;
  unsigned short* xbf = (unsigned short*)p;           p += (size_t)NROWS * FDIM * 2;
  const size_t need = (size_t)(p - (char*)d_ws);
  const bool big = ws_size >= need;

  if (big) {
    convert_fused<<<dim3(16384 + 256), dim3(256), 0, stream>>>(x, xbf, W, Wt, sumE);
    gemm_score_st<<<dim3(2048), dim3(256), 0, stream>>>(xbf, Wt, b, u, spart);
    pool_score<<<dim3(2048), dim3(256), 0, stream>>>(xbf, spart, sumE, ppool);
    pool_reduce<<<dim3(32), dim3(256), 0, stream>>>(ppool, sumE, out);
  } else {
    hipMemsetAsync(sumE, 0, sizeof(float), stream);
    hipMemsetAsync(d_out, 0, (size_t)out_size * sizeof(float), stream);
    convert_W_f<<<dim3(256), dim3(256), 0, stream>>>(W, Wt);
    gemm_score_f32<<<dim3(2048), dim3(256), 0, stream>>>(x, Wt, b, u, spart);
    score_exp<<<dim3(NROWS / 256), dim3(256), 0, stream>>>(spart, sumE);
    pool_k<<<dim3(512), dim3(256), 0, stream>>>(x, spart, sumE, out);
  }
}